// Round 1
// baseline (2795.573 us; speedup 1.0000x reference)
//
#include <hip/hip_runtime.h>
#include <math.h>

#define BB 2
#define NN 512
#define SDIM 384
#define ZDIM 128
#define HH 12
#define CDIM 16
#define PQ 4
#define PV 8
#define BN (BB*NN)        // 1024
#define CATD 2112
#define QKV 192           // H*C
#define QPD 144           // H*PQ*3
#define VPD 288           // H*PV*3

#define WL  0.57735026918962576f
#define LAM 0.06804138174397717f   // wL*wC/2, wC = sqrt(2/(9*PQ))

// workspace layout (float offsets)
#define OFF_Q    0
#define OFF_K    (OFF_Q  + BN*QKV)      // 196608
#define OFF_V    (OFF_K  + BN*QKV)
#define OFF_QP   (OFF_V  + BN*QKV)
#define OFF_KP   (OFF_QP + BN*QPD)
#define OFF_VP   (OFF_KP + BN*QPD)
#define OFF_QQ   (OFF_VP + BN*VPD)
#define OFF_KK   (OFF_QQ + BN*HH)
#define OFF_BIAS (OFF_KK + BN*HH)       // [b,i,j,h] = p*12+h
#define OFF_CAT  (OFF_BIAS + (size_t)BN*NN*HH)
// total = 9,658,368 floats = 38.6 MB

__device__ __forceinline__ float dot4(float4 a, float4 b) {
    return a.x*b.x + a.y*b.y + a.z*b.z + a.w*b.w;
}

// ---------------- Kernel 1: projections + frame transform -------------------
__global__ __launch_bounds__(256) void k_proj(
    const float* __restrict__ s, const float* __restrict__ Rg, const float* __restrict__ tg,
    const float* __restrict__ Wq, const float* __restrict__ Wk, const float* __restrict__ Wv,
    const float* __restrict__ Wqp, const float* __restrict__ Wkp, const float* __restrict__ Wvp,
    float* __restrict__ ws)
{
    __shared__ float sB[4][SDIM];
    __shared__ float pL[4][576];   // qp_local[0:144) kp_local[144:288) vp_local[288:576)
    __shared__ float sqL[4][96];   // |qp|^2 [0:48), |kp|^2 [48:96)
    __shared__ float Rt[4][12];    // R[0:9), t[9:12)
    const int t = threadIdx.x;
    const int n0 = blockIdx.x * 4;

    for (int rr = 0; rr < 4; ++rr)
        for (int c = t; c < SDIM; c += 256)
            sB[rr][c] = s[(size_t)(n0+rr)*SDIM + c];
    if (t < 48) {
        int rr = t / 12, c = t % 12;
        Rt[rr][c] = (c < 9) ? Rg[(n0+rr)*9 + c] : tg[(n0+rr)*3 + (c-9)];
    }
    __syncthreads();

    for (int col = t; col < 1152; col += 256) {
        const float* W; int wcol, ld;
        if (col < 576) {
            ld = QKV; wcol = col % 192;
            W = (col < 192) ? Wq : (col < 384 ? Wk : Wv);
        } else if (col < 864) {
            ld = QPD;
            if (col < 720) { W = Wqp; wcol = col - 576; }
            else           { W = Wkp; wcol = col - 720; }
        } else { ld = VPD; W = Wvp; wcol = col - 864; }
        float a0=0.f,a1=0.f,a2=0.f,a3=0.f;
        for (int r = 0; r < SDIM; ++r) {
            float wv = W[r*ld + wcol];
            a0 += sB[0][r]*wv; a1 += sB[1][r]*wv; a2 += sB[2][r]*wv; a3 += sB[3][r]*wv;
        }
        float acc[4] = {a0,a1,a2,a3};
        #pragma unroll
        for (int rr = 0; rr < 4; ++rr) {
            int bn = n0 + rr;
            if      (col < 192) ws[OFF_Q + (size_t)bn*QKV + wcol] = acc[rr];
            else if (col < 384) ws[OFF_K + (size_t)bn*QKV + wcol] = acc[rr];
            else if (col < 576) ws[OFF_V + (size_t)bn*QKV + wcol] = acc[rr];
            else if (col < 720) pL[rr][wcol]       = acc[rr];
            else if (col < 864) pL[rr][144 + wcol] = acc[rr];
            else                pL[rr][288 + wcol] = acc[rr];
        }
    }
    __syncthreads();

    for (int task = t; task < 768; task += 256) {
        int rr = task / 192, pt = task % 192;
        int off = (pt < 48) ? pt*3 : (pt < 96 ? 144 + (pt-48)*3 : 288 + (pt-96)*3);
        float p0 = pL[rr][off], p1 = pL[rr][off+1], p2 = pL[rr][off+2];
        const float* R = Rt[rr];
        float gx = R[0]*p0 + R[1]*p1 + R[2]*p2 + R[9];
        float gy = R[3]*p0 + R[4]*p1 + R[5]*p2 + R[10];
        float gz = R[6]*p0 + R[7]*p1 + R[8]*p2 + R[11];
        int bn = n0 + rr;
        if (pt < 48) {
            int o = pt*3;
            ws[OFF_QP + (size_t)bn*QPD + o]   = gx;
            ws[OFF_QP + (size_t)bn*QPD + o+1] = gy;
            ws[OFF_QP + (size_t)bn*QPD + o+2] = gz;
            sqL[rr][pt] = gx*gx + gy*gy + gz*gz;
        } else if (pt < 96) {
            int o = (pt-48)*3;
            ws[OFF_KP + (size_t)bn*QPD + o]   = gx;
            ws[OFF_KP + (size_t)bn*QPD + o+1] = gy;
            ws[OFF_KP + (size_t)bn*QPD + o+2] = gz;
            sqL[rr][pt] = gx*gx + gy*gy + gz*gz;
        } else {
            int o = (pt-96)*3;
            ws[OFF_VP + (size_t)bn*VPD + o]   = gx;
            ws[OFF_VP + (size_t)bn*VPD + o+1] = gy;
            ws[OFF_VP + (size_t)bn*VPD + o+2] = gz;
        }
    }
    __syncthreads();

    if (t < 96) {
        int rr = t / 24, u = t % 24;
        if (u < 12) {
            float sm = sqL[rr][u*4] + sqL[rr][u*4+1] + sqL[rr][u*4+2] + sqL[rr][u*4+3];
            ws[OFF_QQ + (size_t)(n0+rr)*HH + u] = sm;
        } else {
            int h = u - 12;
            float sm = sqL[rr][48+h*4] + sqL[rr][48+h*4+1] + sqL[rr][48+h*4+2] + sqL[rr][48+h*4+3];
            ws[OFF_KK + (size_t)(n0+rr)*HH + h] = sm;
        }
    }
}

// ---------------- Kernel 2: pair bias  b[p,h] = z[p,:] @ Wb ------------------
__global__ __launch_bounds__(256) void k_bias(
    const float* __restrict__ z, const float* __restrict__ Wb, float* __restrict__ ws)
{
    __shared__ float WbT[HH*ZDIM];   // [h][zc]
    const int t = threadIdx.x;
    for (int e = t; e < HH*ZDIM; e += 256) {
        int h = e >> 7, zc = e & 127;
        WbT[e] = Wb[zc*HH + h];
    }
    __syncthreads();
    const int p = blockIdx.x*256 + t;     // 0..524287
    const float4* z4 = (const float4*)z;
    const float4* W4 = (const float4*)WbT;
    float acc[HH];
    #pragma unroll
    for (int h = 0; h < HH; ++h) acc[h] = 0.f;
    #pragma unroll 4
    for (int q = 0; q < 32; ++q) {
        float4 zq = z4[(size_t)p*32 + q];
        #pragma unroll
        for (int h = 0; h < HH; ++h) {
            float4 wq = W4[h*32 + q];
            acc[h] += dot4(zq, wq);
        }
    }
    float4* b4 = (float4*)(ws + OFF_BIAS);
    b4[(size_t)p*3 + 0] = make_float4(acc[0], acc[1], acc[2],  acc[3]);
    b4[(size_t)p*3 + 1] = make_float4(acc[4], acc[5], acc[6],  acc[7]);
    b4[(size_t)p*3 + 2] = make_float4(acc[8], acc[9], acc[10], acc[11]);
}

// ---------------- Kernel 3: fused attention per (b,i) -----------------------
__global__ __launch_bounds__(256) void k_attn(
    const float* __restrict__ z, const float* __restrict__ Rg, const float* __restrict__ tg,
    const float* __restrict__ hw, float* __restrict__ ws)
{
    __shared__ float qrow[QKV];
    __shared__ float qpL[QPD];
    __shared__ float qqL[HH];
    __shared__ float gammaL[HH];
    __shared__ float RiL[9];
    __shared__ float tiL[3];
    __shared__ float aL[HH*516];    // logits -> attention, stride 516
    __shared__ float zT[16*132];    // z tile [j_loc][zc], stride 132
    __shared__ float optg[VPD];

    const int t = threadIdx.x;
    const int bi = blockIdx.x;
    const int b = bi >> 9, i = bi & 511;
    const int bN = b * NN;

    if (t < QKV) qrow[t] = ws[OFF_Q + (size_t)bi*QKV + t];
    if (t < QPD) qpL[t]  = ws[OFF_QP + (size_t)bi*QPD + t];
    if (t >= 192 && t < 204) qqL[t-192] = ws[OFF_QQ + (size_t)bi*HH + (t-192)];
    if (t >= 204 && t < 216) {
        float x = hw[t-204];
        gammaL[t-204] = (x > 20.f) ? x : log1pf(expf(x));
    }
    if (t >= 216 && t < 225) RiL[t-216] = Rg[bi*9 + (t-216)];
    if (t >= 225 && t < 228) tiL[t-225] = tg[bi*3 + (t-225)];
    __syncthreads();

    // ---- pass 1: logits for all (h, j) ----
    {
        const int h = t & 15;
        const int j0 = t >> 4;
        if (h < HH) {
            const float4* q4 = (const float4*)&qrow[h*16];
            float4 qv0 = q4[0], qv1 = q4[1], qv2 = q4[2], qv3 = q4[3];
            const float4* p4 = (const float4*)&qpL[h*12];
            float4 pv0 = p4[0], pv1 = p4[1], pv2 = p4[2];
            const float qqv = qqL[h];
            const float gam = gammaL[h];
            for (int j = j0; j < NN; j += 16) {
                const int bj = bN + j;
                const float4* k4 = (const float4*)(ws + OFF_K + (size_t)bj*QKV + h*16);
                float scal = dot4(qv0,k4[0]) + dot4(qv1,k4[1]) + dot4(qv2,k4[2]) + dot4(qv3,k4[3]);
                const float4* kp4 = (const float4*)(ws + OFF_KP + (size_t)bj*QPD + h*12);
                float qk = dot4(pv0,kp4[0]) + dot4(pv1,kp4[1]) + dot4(pv2,kp4[2]);
                float kkv = ws[OFF_KK + (size_t)bj*HH + h];
                float bv  = ws[OFF_BIAS + ((size_t)(bN + i)*NN + j)*HH + h];
                float dist2 = qqv + kkv - 2.f*qk;
                aL[h*516 + j] = WL*(scal*0.25f + bv) - LAM*gam*dist2;
            }
        }
    }
    __syncthreads();

    // ---- softmax per head (one wave handles h = wave, wave+4, wave+8) ----
    {
        const int wave = t >> 6, lane = t & 63;
        for (int h = wave; h < HH; h += 4) {
            float m = -1e30f;
            for (int j = lane; j < NN; j += 64) m = fmaxf(m, aL[h*516 + j]);
            #pragma unroll
            for (int off = 32; off > 0; off >>= 1) m = fmaxf(m, __shfl_xor(m, off));
            float ssum = 0.f;
            for (int j = lane; j < NN; j += 64) {
                float e = expf(aL[h*516 + j] - m);
                aL[h*516 + j] = e;
                ssum += e;
            }
            #pragma unroll
            for (int off = 32; off > 0; off >>= 1) ssum += __shfl_xor(ssum, off);
            float inv = 1.f / ssum;
            for (int j = lane; j < NN; j += 64) aL[h*516 + j] *= inv;
        }
    }
    __syncthreads();

    // ---- pass 2: accumulate opair / o / opt_g as float4 slots ----
    // virtual slot space: [0,384) opair(h,zc4), [384,432) o(h,c4), [432,504) opt_g
    const int s1 = t;                       // always opair-type (t<256<384)
    const int h1 = s1 >> 5, o1 = s1 & 31;
    const int s2 = t + 256;
    int type2, h2 = 0, o2 = 0;
    if (s2 < 384)      { type2 = 0; h2 = s2 >> 5;  o2 = s2 & 31; }
    else if (s2 < 432) { type2 = 1; int u = s2-384; h2 = u >> 2; o2 = u; }
    else if (s2 < 504) { type2 = 2; int u = s2-432; h2 = u / 6;  o2 = u; }
    else type2 = 3;

    float4 acc1 = make_float4(0,0,0,0), acc2 = make_float4(0,0,0,0);
    const float4* zT4c = (const float4*)zT;
    const float4* v4   = (const float4*)(ws + OFF_V);
    const float4* vp4  = (const float4*)(ws + OFF_VP);
    const size_t zbase = ((size_t)(bN + i)) * NN * ZDIM;

    for (int jt = 0; jt < NN; jt += 16) {
        __syncthreads();
        for (int e = t; e < 2048; e += 256) {
            int jl = e >> 7, zc = e & 127;
            zT[jl*132 + zc] = z[zbase + (size_t)(jt+jl)*ZDIM + zc];
        }
        __syncthreads();
        for (int jl = 0; jl < 16; ++jl) {
            const int j = jt + jl;
            float a1 = aL[h1*516 + j];
            float4 zq = zT4c[jl*33 + o1];
            acc1.x += a1*zq.x; acc1.y += a1*zq.y; acc1.z += a1*zq.z; acc1.w += a1*zq.w;
            if (type2 == 0) {
                float a2 = aL[h2*516 + j];
                float4 q2 = zT4c[jl*33 + o2];
                acc2.x += a2*q2.x; acc2.y += a2*q2.y; acc2.z += a2*q2.z; acc2.w += a2*q2.w;
            } else if (type2 == 1) {
                float a2 = aL[h2*516 + j];
                float4 q2 = v4[(size_t)(bN + j)*48 + o2];
                acc2.x += a2*q2.x; acc2.y += a2*q2.y; acc2.z += a2*q2.z; acc2.w += a2*q2.w;
            } else if (type2 == 2) {
                float a2 = aL[h2*516 + j];
                float4 q2 = vp4[(size_t)(bN + j)*72 + o2];
                acc2.x += a2*q2.x; acc2.y += a2*q2.y; acc2.z += a2*q2.z; acc2.w += a2*q2.w;
            }
        }
    }

    // ---- write out: cat row = [o(192) | opt(288) | opt_norm(96) | opair(1536)] ----
    float4* cat4 = (float4*)(ws + OFF_CAT);
    const size_t cb = (size_t)bi * 528;   // 2112/4
    cat4[cb + 144 + s1] = acc1;           // opair base = 576 floats = 144 f4
    if (type2 == 0)      cat4[cb + 144 + s2] = acc2;
    else if (type2 == 1) cat4[cb + o2] = acc2;                 // o at offset 0
    else if (type2 == 2) ((float4*)optg)[o2] = acc2;           // stage opt_g
    __syncthreads();

    if (t < 96) {
        int h = t >> 3, p = t & 7;
        int o = h*24 + p*3;
        float d0 = optg[o]   - tiL[0];
        float d1 = optg[o+1] - tiL[1];
        float d2 = optg[o+2] - tiL[2];
        // opt[x] = sum_y R[y,x] * d[y]  (R^T d)
        float ox = RiL[0]*d0 + RiL[3]*d1 + RiL[6]*d2;
        float oy = RiL[1]*d0 + RiL[4]*d1 + RiL[7]*d2;
        float oz = RiL[2]*d0 + RiL[5]*d1 + RiL[8]*d2;
        float* cat = ws + OFF_CAT + (size_t)bi*CATD;
        cat[192 + o]     = ox;
        cat[192 + o + 1] = oy;
        cat[192 + o + 2] = oz;
        cat[480 + h*8 + p] = sqrtf(ox*ox + oy*oy + oz*oz + 1e-8f);
    }
}

// ---------------- Kernel 4: out = cat @ Wout --------------------------------
__global__ __launch_bounds__(256) void k_out(
    const float* __restrict__ Wout, const float* __restrict__ ws, float* __restrict__ out)
{
    __shared__ float catT[CATD*4];   // transposed [r][row]
    const int t = threadIdx.x;
    const int row0 = blockIdx.x * 4;
    const float* cat = ws + OFF_CAT;
    for (int rr = 0; rr < 4; ++rr)
        for (int c = t; c < CATD; c += 256)
            catT[c*4 + rr] = cat[(size_t)(row0+rr)*CATD + c];
    __syncthreads();

    const int c1 = t, c2 = 256 + t;
    float a1[4] = {0,0,0,0}, a2[4] = {0,0,0,0};
    const float4* cT4 = (const float4*)catT;
    #pragma unroll 4
    for (int r = 0; r < CATD; ++r) {
        float4 cv = cT4[r];
        float w1 = Wout[(size_t)r*384 + c1];
        a1[0] += cv.x*w1; a1[1] += cv.y*w1; a1[2] += cv.z*w1; a1[3] += cv.w*w1;
        if (t < 128) {
            float w2 = Wout[(size_t)r*384 + c2];
            a2[0] += cv.x*w2; a2[1] += cv.y*w2; a2[2] += cv.z*w2; a2[3] += cv.w*w2;
        }
    }
    #pragma unroll
    for (int rr = 0; rr < 4; ++rr) {
        out[(size_t)(row0+rr)*384 + c1] = a1[rr];
        if (t < 128) out[(size_t)(row0+rr)*384 + c2] = a2[rr];
    }
}

extern "C" void kernel_launch(void* const* d_in, const int* in_sizes, int n_in,
                              void* d_out, int out_size, void* d_ws, size_t ws_size,
                              hipStream_t stream)
{
    const float* s    = (const float*)d_in[0];
    const float* z    = (const float*)d_in[1];
    const float* R    = (const float*)d_in[2];
    const float* tt   = (const float*)d_in[3];
    const float* Wq   = (const float*)d_in[4];
    const float* Wk   = (const float*)d_in[5];
    const float* Wv   = (const float*)d_in[6];
    const float* Wqp  = (const float*)d_in[7];
    const float* Wkp  = (const float*)d_in[8];
    const float* Wvp  = (const float*)d_in[9];
    const float* Wb   = (const float*)d_in[10];
    const float* hw   = (const float*)d_in[11];
    const float* Wout = (const float*)d_in[12];
    float* ws  = (float*)d_ws;
    float* out = (float*)d_out;

    hipLaunchKernelGGL(k_proj, dim3(BN/4),        dim3(256), 0, stream,
                       s, R, tt, Wq, Wk, Wv, Wqp, Wkp, Wvp, ws);
    hipLaunchKernelGGL(k_bias, dim3(BN*NN/256),   dim3(256), 0, stream, z, Wb, ws);
    hipLaunchKernelGGL(k_attn, dim3(BN),          dim3(256), 0, stream, z, R, tt, hw, ws);
    hipLaunchKernelGGL(k_out,  dim3(BN/4),        dim3(256), 0, stream, Wout, ws, out);
}

// Round 2
// 1007.810 us; speedup vs baseline: 2.7739x; 2.7739x over previous
//
#include <hip/hip_runtime.h>
#include <math.h>

#define BB 2
#define NN 512
#define SDIM 384
#define ZDIM 128
#define HH 12
#define CDIM 16
#define PQ 4
#define PV 8
#define BN (BB*NN)        // 1024
#define CATD 2112

#define WL  0.57735026918962576f
#define LAM 0.06804138174397717f   // wL*wC/2, wC = sqrt(2/(9*PQ))

// ---- workspace layout (float offsets) ----
#define OFF_Q    0                         // [1024][192] rows
#define OFF_QP   196608                    // [1024][144] rows
#define OFF_QQ   344064                    // [1024][12]
#define OFF_KT4  356352                    // f4: [2][48][512]  (c4-group major, n minor)
#define OFF_KPT4 552960                    // f4: [2][36][512]
#define OFF_KKT  700416                    // [2][12][512]
#define OFF_V    712704                    // [1024][192] rows (f4 view [1024][48])
#define OFF_VP   909312                    // [1024][288] rows (f4 view [1024][72])
#define OFF_BIAS 1204224                   // [2][512 i][12 h][512 j]
#define OFF_CAT  7495680                   // [1024][2112]
// end = 9658368 floats = 38.63 MB

__device__ __forceinline__ float dot4(float4 a, float4 b) {
    return a.x*b.x + a.y*b.y + a.z*b.z + a.w*b.w;
}
__device__ __forceinline__ void fma4(float4& a, float s, float4 b) {
    a.x += s*b.x; a.y += s*b.y; a.z += s*b.z; a.w += s*b.w;
}
__device__ __forceinline__ void add4(float4& a, float4 b) {
    a.x += b.x; a.y += b.y; a.z += b.z; a.w += b.w;
}

// ---------------- Kernel 1: projections + frame transform -------------------
// 2 rows per block, 512 blocks. s rows read via scalar loads (uniform).
__global__ __launch_bounds__(256) void k_proj(
    const float* __restrict__ s, const float* __restrict__ Rg, const float* __restrict__ tg,
    const float* __restrict__ Wq, const float* __restrict__ Wk, const float* __restrict__ Wv,
    const float* __restrict__ Wqp, const float* __restrict__ Wkp, const float* __restrict__ Wvp,
    float* __restrict__ ws)
{
    __shared__ float4 pL4[2][144];   // point projections (local frame), rows 0/1
    __shared__ float  sqL[2][96];    // |qp|^2 [0:48), |kp|^2 [48:96)
    __shared__ float  Rt[2][12];
    const int t = threadIdx.x;
    const int n0 = blockIdx.x * 2;
    const int b  = n0 >> 9;
    const int nloc = n0 & 511;

    if (t < 24) {
        int rr = t / 12, c = t % 12;
        Rt[rr][c] = (c < 9) ? Rg[(n0+rr)*9 + c] : tg[(n0+rr)*3 + (c-9)];
    }
    const float* s0 = s + (size_t)n0*SDIM;
    const float* s1 = s0 + SDIM;
    __syncthreads();

    float4* Q4g  = (float4*)(ws + OFF_Q);
    float4* V4g  = (float4*)(ws + OFF_V);
    float4* KT4g = (float4*)(ws + OFF_KT4);

    for (int it = 0; it < 2; ++it) {
        int g = t + it*256;
        if (g >= 288) break;
        const float4* W4; int wc4, ld4, dst;
        if (g < 48)       { W4 = (const float4*)Wq;  wc4 = g;     ld4 = 48; dst = 0; }
        else if (g < 96)  { W4 = (const float4*)Wk;  wc4 = g-48;  ld4 = 48; dst = 1; }
        else if (g < 144) { W4 = (const float4*)Wv;  wc4 = g-96;  ld4 = 48; dst = 2; }
        else if (g < 180) { W4 = (const float4*)Wqp; wc4 = g-144; ld4 = 36; dst = 3; }
        else if (g < 216) { W4 = (const float4*)Wkp; wc4 = g-180; ld4 = 36; dst = 4; }
        else              { W4 = (const float4*)Wvp; wc4 = g-216; ld4 = 72; dst = 5; }
        float4 acc0 = {0,0,0,0}, acc1 = {0,0,0,0};
        #pragma unroll 4
        for (int r = 0; r < SDIM; ++r) {
            float4 wv = W4[r*ld4 + wc4];
            float f0 = s0[r], f1 = s1[r];
            fma4(acc0, f0, wv);
            fma4(acc1, f1, wv);
        }
        if (dst == 0) {
            Q4g[(size_t)n0*48 + wc4] = acc0;
            Q4g[(size_t)(n0+1)*48 + wc4] = acc1;
        } else if (dst == 1) {
            size_t base = ((size_t)(b*48 + wc4))*512 + nloc;
            KT4g[base] = acc0; KT4g[base+1] = acc1;
        } else if (dst == 2) {
            V4g[(size_t)n0*48 + wc4] = acc0;
            V4g[(size_t)(n0+1)*48 + wc4] = acc1;
        } else if (dst == 3) {
            pL4[0][wc4] = acc0; pL4[1][wc4] = acc1;
        } else if (dst == 4) {
            pL4[0][36+wc4] = acc0; pL4[1][36+wc4] = acc1;
        } else {
            pL4[0][72+wc4] = acc0; pL4[1][72+wc4] = acc1;
        }
    }
    __syncthreads();

    // local -> global frame
    for (int task = t; task < 384; task += 256) {
        int rr = task / 192, pt = task % 192;
        const float* pl = (const float*)pL4[rr];
        int off = (pt < 48) ? pt*3 : (pt < 96 ? 144 + (pt-48)*3 : 288 + (pt-96)*3);
        float p0 = pl[off], p1 = pl[off+1], p2 = pl[off+2];
        const float* R = Rt[rr];
        float g0 = R[0]*p0 + R[1]*p1 + R[2]*p2 + R[9];
        float g1 = R[3]*p0 + R[4]*p1 + R[5]*p2 + R[10];
        float g2 = R[6]*p0 + R[7]*p1 + R[8]*p2 + R[11];
        int bn = n0 + rr, n = bn & 511;
        if (pt < 48) {
            int o = pt*3;
            float* d = ws + OFF_QP + (size_t)bn*144 + o;
            d[0] = g0; d[1] = g1; d[2] = g2;
            sqL[rr][pt] = g0*g0 + g1*g1 + g2*g2;
        } else if (pt < 96) {
            int pc = (pt-48)*3;
            float gg[3] = {g0,g1,g2};
            #pragma unroll
            for (int x = 0; x < 3; ++x) {
                int pcx = pc + x;
                ws[OFF_KPT4 + (((size_t)(b*36 + (pcx>>2)))*512 + n)*4 + (pcx&3)] = gg[x];
            }
            sqL[rr][pt] = g0*g0 + g1*g1 + g2*g2;
        } else {
            int o = (pt-96)*3;
            float* d = ws + OFF_VP + (size_t)bn*288 + o;
            d[0] = g0; d[1] = g1; d[2] = g2;
        }
    }
    __syncthreads();

    if (t < 48) {
        int rr = t / 24, u = t % 24;
        int bn = n0 + rr, n = bn & 511;
        if (u < 12) {
            float sm = sqL[rr][u*4] + sqL[rr][u*4+1] + sqL[rr][u*4+2] + sqL[rr][u*4+3];
            ws[OFF_QQ + (size_t)bn*12 + u] = sm;
        } else {
            int h = u - 12;
            float sm = sqL[rr][48+h*4] + sqL[rr][48+h*4+1] + sqL[rr][48+h*4+2] + sqL[rr][48+h*4+3];
            ws[OFF_KKT + ((size_t)(b*12 + h))*512 + n] = sm;
        }
    }
}

// ---------------- Kernel 2: pair bias (Wb via scalar loads) -----------------
__global__ __launch_bounds__(256) void k_bias(
    const float* __restrict__ z, const float* __restrict__ Wb, float* __restrict__ ws)
{
    const int t = threadIdx.x;
    const int p = blockIdx.x*256 + t;          // (b,i,j) flat
    const float4* z4 = (const float4*)z + (size_t)p*32;
    float acc[HH];
    #pragma unroll
    for (int h = 0; h < HH; ++h) acc[h] = 0.f;
    #pragma unroll 4
    for (int q = 0; q < 32; ++q) {
        float4 zq = z4[q];
        const float* wb = Wb + q*48;           // uniform -> s_load
        #pragma unroll
        for (int h = 0; h < HH; ++h)
            acc[h] += zq.x*wb[h] + zq.y*wb[12+h] + zq.z*wb[24+h] + zq.w*wb[36+h];
    }
    const int bi = p >> 9, j = p & 511;
    float* BI = ws + OFF_BIAS + (size_t)bi*HH*512;
    #pragma unroll
    for (int h = 0; h < HH; ++h)
        BI[h*512 + j] = acc[h];                // coalesced (lanes = consecutive j)
}

// ---------------- Kernel 3: fused attention per (b,i) -----------------------
__global__ __launch_bounds__(512) void k_attn(
    const float* __restrict__ z, const float* __restrict__ Rg, const float* __restrict__ tg,
    const float* __restrict__ hw, float* __restrict__ ws)
{
    __shared__ __align__(16) float aL[HH*516];   // logits -> attention, stride 516
    __shared__ float4 optgS4[72];
    __shared__ float RiL[9], tiL[3];

    const int t = threadIdx.x;
    const int bi = blockIdx.x;
    const int b = bi >> 9;

    if (t < 9)             RiL[t]   = Rg[bi*9 + t];
    if (t >= 9 && t < 12)  tiL[t-9] = tg[bi*3 + (t-9)];

    // gamma (uniform, per-thread registers)
    float gam[HH];
    #pragma unroll
    for (int h = 0; h < HH; ++h) {
        float x = hw[h];
        gam[h] = (x > 20.f) ? x : log1pf(__expf(x));
    }

    // ---- phase A: logits, thread <-> j ----
    {
        const int j = t;
        const float4* Q4u  = (const float4*)(ws + OFF_Q  + (size_t)bi*192);
        const float4* QP4u = (const float4*)(ws + OFF_QP + (size_t)bi*144);
        const float*  QQu  = ws + OFF_QQ + (size_t)bi*12;
        const float4* KT4  = (const float4*)(ws + OFF_KT4)  + (size_t)b*48*512;
        const float4* KPT4 = (const float4*)(ws + OFF_KPT4) + (size_t)b*36*512;
        const float*  KKT  = ws + OFF_KKT  + (size_t)b*12*512;
        const float*  BI   = ws + OFF_BIAS + (size_t)bi*HH*512;
        for (int h = 0; h < HH; ++h) {
            float scal = 0.f, qk = 0.f;
            #pragma unroll
            for (int cg = 0; cg < 4; ++cg)
                scal += dot4(Q4u[h*4+cg], KT4[(h*4+cg)*512 + j]);
            #pragma unroll
            for (int pg = 0; pg < 3; ++pg)
                qk += dot4(QP4u[h*3+pg], KPT4[(h*3+pg)*512 + j]);
            float dist2 = QQu[h] + KKT[h*512 + j] - 2.f*qk;
            aL[h*516 + j] = WL*(scal*0.25f + BI[h*512 + j]) - LAM*gam[h]*dist2;
        }
    }
    __syncthreads();

    // ---- phase B: softmax per head ----
    {
        const int w = t >> 6, lane = t & 63;
        for (int h = w; h < HH; h += 8) {
            float* row = aL + h*516;
            float m = -1e30f;
            #pragma unroll
            for (int k = 0; k < 8; ++k) m = fmaxf(m, row[lane + 64*k]);
            #pragma unroll
            for (int off = 32; off > 0; off >>= 1) m = fmaxf(m, __shfl_xor(m, off));
            float ssum = 0.f;
            #pragma unroll
            for (int k = 0; k < 8; ++k) {
                float e = __expf(row[lane + 64*k] - m);
                row[lane + 64*k] = e;
                ssum += e;
            }
            #pragma unroll
            for (int off = 32; off > 0; off >>= 1) ssum += __shfl_xor(ssum, off);
            float inv = 1.f / ssum;
            #pragma unroll
            for (int k = 0; k < 8; ++k) row[lane + 64*k] *= inv;
        }
    }
    __syncthreads();

    // ---- phase C: accumulate opair/o/opt_g; 3 j-segments x 168 slot-threads ----
    float4 acc0 = {0,0,0,0}, acc1 = {0,0,0,0}, acc2 = {0,0,0,0};
    int seg = 0, u = 0, typ = 3, hg = 0;
    if (t < 504) {
        seg = (t >= 336) ? 2 : (t >= 168) ? 1 : 0;
        u = t - seg*168;
        const int j0 = seg*172, j1 = (seg == 2) ? 512 : j0 + 172;
        if (u < 128) {
            typ = 0; hg = u >> 5;
            const int zc4 = u & 31;
            const float4* Zp = (const float4*)z + (size_t)bi*512*32 + zc4;
            const float* a0p = aL + hg*516;
            const float* a1p = aL + (hg+4)*516;
            const float* a2p = aL + (hg+8)*516;
            for (int jt = j0; jt < j1; jt += 4) {
                float4 av0 = *(const float4*)(a0p + jt);
                float4 av1 = *(const float4*)(a1p + jt);
                float4 av2 = *(const float4*)(a2p + jt);
                #pragma unroll
                for (int e = 0; e < 4; ++e) {
                    float4 zq = Zp[(size_t)(jt+e)*32];
                    fma4(acc0, ((const float*)&av0)[e], zq);
                    fma4(acc1, ((const float*)&av1)[e], zq);
                    fma4(acc2, ((const float*)&av2)[e], zq);
                }
            }
        } else if (u < 144) {
            typ = 1; const int v0 = u - 128;
            const int c4 = v0 & 3; hg = v0 >> 2;
            const float4* Vp = (const float4*)(ws + OFF_V) + (size_t)b*512*48;
            const float* a0p = aL + hg*516;
            const float* a1p = aL + (hg+4)*516;
            const float* a2p = aL + (hg+8)*516;
            for (int jt = j0; jt < j1; jt += 4) {
                float4 av0 = *(const float4*)(a0p + jt);
                float4 av1 = *(const float4*)(a1p + jt);
                float4 av2 = *(const float4*)(a2p + jt);
                #pragma unroll
                for (int e = 0; e < 4; ++e) {
                    size_t jb = (size_t)(jt+e)*48;
                    fma4(acc0, ((const float*)&av0)[e], Vp[jb + (hg  )*4 + c4]);
                    fma4(acc1, ((const float*)&av1)[e], Vp[jb + (hg+4)*4 + c4]);
                    fma4(acc2, ((const float*)&av2)[e], Vp[jb + (hg+8)*4 + c4]);
                }
            }
        } else {
            typ = 2; const int v0 = u - 144;
            const int po = v0 % 6; hg = v0 / 6;
            const float4* VPp = (const float4*)(ws + OFF_VP) + (size_t)b*512*72;
            const float* a0p = aL + hg*516;
            const float* a1p = aL + (hg+4)*516;
            const float* a2p = aL + (hg+8)*516;
            for (int jt = j0; jt < j1; jt += 4) {
                float4 av0 = *(const float4*)(a0p + jt);
                float4 av1 = *(const float4*)(a1p + jt);
                float4 av2 = *(const float4*)(a2p + jt);
                #pragma unroll
                for (int e = 0; e < 4; ++e) {
                    size_t jb = (size_t)(jt+e)*72;
                    fma4(acc0, ((const float*)&av0)[e], VPp[jb + (hg  )*6 + po]);
                    fma4(acc1, ((const float*)&av1)[e], VPp[jb + (hg+4)*6 + po]);
                    fma4(acc2, ((const float*)&av2)[e], VPp[jb + (hg+8)*6 + po]);
                }
            }
        }
    }
    __syncthreads();                       // all reads of aL done
    float4* sc4 = (float4*)aL;             // reuse aL as reduction scratch
    if (t < 504 && seg > 0) {
        int si = ((seg-1)*168 + u)*3;
        sc4[si] = acc0; sc4[si+1] = acc1; sc4[si+2] = acc2;
    }
    __syncthreads();

    if (t < 168) {
        #pragma unroll
        for (int ss = 0; ss < 2; ++ss) {
            int si = (ss*168 + t)*3;
            add4(acc0, sc4[si]); add4(acc1, sc4[si+1]); add4(acc2, sc4[si+2]);
        }
        float4* cat4 = (float4*)(ws + OFF_CAT);
        const size_t cb = (size_t)bi * 528;          // 2112/4
        if (typ == 0) {
            const int zc4 = u & 31;
            cat4[cb + 144 + (hg  )*32 + zc4] = acc0;
            cat4[cb + 144 + (hg+4)*32 + zc4] = acc1;
            cat4[cb + 144 + (hg+8)*32 + zc4] = acc2;
        } else if (typ == 1) {
            const int c4 = (u-128) & 3;
            cat4[cb + (hg  )*4 + c4] = acc0;
            cat4[cb + (hg+4)*4 + c4] = acc1;
            cat4[cb + (hg+8)*4 + c4] = acc2;
        } else {
            const int po = (u-144) % 6;
            optgS4[(hg  )*6 + po] = acc0;
            optgS4[(hg+4)*6 + po] = acc1;
            optgS4[(hg+8)*6 + po] = acc2;
        }
    }
    __syncthreads();

    if (t < 96) {
        const float* og = (const float*)optgS4;
        int h = t >> 3, p = t & 7;
        int o = h*24 + p*3;
        float d0 = og[o]   - tiL[0];
        float d1 = og[o+1] - tiL[1];
        float d2 = og[o+2] - tiL[2];
        float ox = RiL[0]*d0 + RiL[3]*d1 + RiL[6]*d2;
        float oy = RiL[1]*d0 + RiL[4]*d1 + RiL[7]*d2;
        float oz = RiL[2]*d0 + RiL[5]*d1 + RiL[8]*d2;
        float* cat = ws + OFF_CAT + (size_t)bi*CATD;
        cat[192 + o]     = ox;
        cat[192 + o + 1] = oy;
        cat[192 + o + 2] = oz;
        cat[480 + h*8 + p] = sqrtf(ox*ox + oy*oy + oz*oz + 1e-8f);
    }
}

// ---------------- Kernel 4: out = cat @ Wout (cat via scalar loads) ---------
__global__ __launch_bounds__(384) void k_out(
    const float* __restrict__ Wout, const float* __restrict__ ws, float* __restrict__ out)
{
    const int t = threadIdx.x;                 // col 0..383
    const int row0 = blockIdx.x * 4;
    const float* c0 = ws + OFF_CAT + (size_t)(row0+0)*CATD;
    const float* c1 = c0 + CATD;
    const float* c2 = c1 + CATD;
    const float* c3 = c2 + CATD;
    float a0 = 0.f, a1 = 0.f, a2 = 0.f, a3 = 0.f;
    #pragma unroll 8
    for (int r = 0; r < CATD; ++r) {
        float w = Wout[(size_t)r*384 + t];
        a0 += c0[r]*w; a1 += c1[r]*w; a2 += c2[r]*w; a3 += c3[r]*w;
    }
    out[(size_t)(row0+0)*384 + t] = a0;
    out[(size_t)(row0+1)*384 + t] = a1;
    out[(size_t)(row0+2)*384 + t] = a2;
    out[(size_t)(row0+3)*384 + t] = a3;
}

extern "C" void kernel_launch(void* const* d_in, const int* in_sizes, int n_in,
                              void* d_out, int out_size, void* d_ws, size_t ws_size,
                              hipStream_t stream)
{
    const float* s    = (const float*)d_in[0];
    const float* z    = (const float*)d_in[1];
    const float* R    = (const float*)d_in[2];
    const float* tt   = (const float*)d_in[3];
    const float* Wq   = (const float*)d_in[4];
    const float* Wk   = (const float*)d_in[5];
    const float* Wv   = (const float*)d_in[6];
    const float* Wqp  = (const float*)d_in[7];
    const float* Wkp  = (const float*)d_in[8];
    const float* Wvp  = (const float*)d_in[9];
    const float* Wb   = (const float*)d_in[10];
    const float* hw   = (const float*)d_in[11];
    const float* Wout = (const float*)d_in[12];
    float* ws  = (float*)d_ws;
    float* out = (float*)d_out;

    hipLaunchKernelGGL(k_proj, dim3(BN/2),      dim3(256), 0, stream,
                       s, R, tt, Wq, Wk, Wv, Wqp, Wkp, Wvp, ws);
    hipLaunchKernelGGL(k_bias, dim3(BN*NN/256), dim3(256), 0, stream, z, Wb, ws);
    hipLaunchKernelGGL(k_attn, dim3(BN),        dim3(512), 0, stream, z, R, tt, hw, ws);
    hipLaunchKernelGGL(k_out,  dim3(BN/4),      dim3(384), 0, stream, Wout, ws, out);
}